// Round 8
// baseline (325.230 us; speedup 1.0000x reference)
//
#include <hip/hip_runtime.h>
#include <hip/hip_bf16.h>
#include <stdint.h>
#include <stddef.h>

// Causal single-head attention, B=4 S=2048 D=1024. fp32 in/out; bf16 MFMA inside.
// R15: step-count attack. R14 (XCD decode) halved HBM FETCH with zero time
// change -> staging bytes/source are NOT the wall; per-CU block-step
// completion time is (2676 cy/step vs 1475 for the same structure at 4096^3).
// Fixed per-step overhead (barrier+vmcnt drain+ramp) dominates at K=1024.
// Fix: (a) BK 64->128: halves steps/block (16->8), halves barriers per byte,
// 64 MFMA/wave/step; LDS 64KB, 2 blocks/CU (occupancy 20-35% measured null).
// (b) QKV persistent: 768 blocks x 2 jobs (job2 = flat+768: same XCD c, same
// A-band by, bx+12) amortizing prologue/epilogue. XCD decode kept from R14.
// LDS layout stays granule-linear: koff = s*32 + q4*8 (s now 0..3),
// rowblock stride 128 short8. MFMA k-order identical to R14 (bitwise-same).

typedef __hip_bfloat16 bf16;
typedef short short8 __attribute__((ext_vector_type(8)));
typedef short short4v __attribute__((ext_vector_type(4)));
typedef float f32x4 __attribute__((ext_vector_type(4)));

#define BM 128
#define BN 128
#define BK 128
#define MSZ 8192   // B*S
#define DD 1024    // D

__device__ __forceinline__ void cstore(float* p, float v) { *p = v; }
__device__ __forceinline__ void cstore(bf16* p, float v) { *p = __float2bfloat16(v); }

// fp32 -> bf16 downcast, 4 elems/thread
__global__ __launch_bounds__(256)
void f2b(const float* __restrict__ s, bf16* __restrict__ d, int n) {
  const int i = (blockIdx.x * 256 + threadIdx.x) * 4;
  if (i >= n) return;
  const float4 v = *(const float4*)(s + i);
  bf16 t[4] = {__float2bfloat16(v.x), __float2bfloat16(v.y),
               __float2bfloat16(v.z), __float2bfloat16(v.w)};
  *(short4v*)(d + i) = *(short4v*)t;
}

// three weight matrices -> contiguous bf16 block [Wq;Wk;Wv]
__global__ __launch_bounds__(256)
void f2b3(const float* __restrict__ a, const float* __restrict__ b,
          const float* __restrict__ c, bf16* __restrict__ d, int n) {
  const float* s = (blockIdx.y == 0) ? a : (blockIdx.y == 1) ? b : c;
  const int i = (blockIdx.x * 256 + threadIdx.x) * 4;
  if (i >= n) return;
  const float4 v = *(const float4*)(s + i);
  bf16 t[4] = {__float2bfloat16(v.x), __float2bfloat16(v.y),
               __float2bfloat16(v.z), __float2bfloat16(v.w)};
  *(short4v*)(d + (size_t)blockIdx.y * n + i) = *(short4v*)t;
}

// C[M,N] = A[M,K] * B[N,K]^T (both K-contiguous), bf16 in. BK=128.
// MODE 1: QKV — persistent 768 blocks x 2 jobs; bx<16 -> Q|K rows,
//         bx>=16 -> V transposed into C2[D][MS].
// MODE 2: Sc — triangular, XCD pair per batch (544 blocks).
// MODE 3: PV — float out, K clipped at diagonal (512 blocks).
template <int MODE, typename CT>
__global__ __launch_bounds__(256, 2)
void gemm_bt(const bf16* __restrict__ A, const bf16* __restrict__ B,
             CT* __restrict__ C, bf16* __restrict__ C2,
             int lda, int ldb, int ldc, int K,
             long sA, long sB, long sC, float scale) {
  __shared__ short8 As[2048];  // 32 KB: [rb 0..15][G 0..15][r8 0..7]
  __shared__ short8 Bs[2048];  // 32 KB

  const int tid = threadIdx.x;
  const int wave = tid >> 6, lane = tid & 63;
  const int wm = wave >> 1, wn = wave & 1;  // 2x2 wave grid, 64x64 each
  const int l15 = lane & 15, q4 = lane >> 4;
  const int rh = l15 >> 3, r3 = l15 & 7;
  const int sg = lane >> 3, sr = lane & 7;  // staging: lane = (g<<3)|r8
  const int flat = blockIdx.x;
  const int c = flat & 7;  // XCD (flat%8 round-robin)

  // fragment read bases: idx(row,G) = (row>>3)*128 + G*8 + (row&7)
  const int fra = wm * 1024 + rh * 128 + q4 * 8 + r3;
  const int frb = wn * 1024 + rh * 128 + q4 * 8 + r3;
  short8* asw = &As[wave * 512];  // 4 rowblocks * 128 short8 per wave
  short8* bsw = &Bs[wave * 512];

  const int NJOBS = (MODE == 1) ? 2 : 1;

  for (int jb = 0; jb < NJOBS; ++jb) {
    int by, bx, zb;
    if (MODE == 1) {
      // 1536 jobs = 768 blocks x 2; j = flat>>3 + jb*96.
      const int j = (flat >> 3) + jb * 96;
      by = c * 8 + (j & 7);   // same A-band for both jobs
      bx = j >> 3;            // 0..11 then 12..23
      zb = 0;
    } else if (MODE == 2) {
      // 544 = 8 XCD x 68. XCD pair owns batch; halves split tri range 0..135.
      zb = c >> 1;
      const int t = (c & 1) * 68 + (flat >> 3);
      int y = (int)((__fsqrt_rn(8.f * (float)t + 1.f) - 1.f) * 0.5f);
      while ((y + 1) * (y + 2) / 2 <= t) y++;
      while (y * (y + 1) / 2 > t) y--;
      by = y;
      bx = t - y * (y + 1) / 2;
    } else {
      // 512 = 8 XCD x 64. XCD pair owns batch; bx-inner, by parity-desc.
      const int j = flat >> 3;
      zb = c >> 1;
      bx = j & 7;
      by = 2 * (7 - (j >> 3)) + (c & 1);
    }

    const int bm0 = by * BM, bn0 = bx * BN;
    const bf16* Az = A + (long)zb * sA;
    const bf16* Bz = B + (long)zb * sB;
    CT* Cz = C + (long)zb * sC;

    const bf16* apg = Az + (size_t)(bm0 + wave * 32 + sr) * lda + sg * 8;
    const bf16* bpg = Bz + (size_t)(bn0 + wave * 32 + sr) * ldb + sg * 8;

    const int Ke = (MODE == 3) ? min(K, (by + 1) * BM) : K;

    f32x4 acc[4][4] = {};

    for (int k0 = 0; k0 < Ke; k0 += BK) {
#pragma unroll
      for (int jj = 0; jj < 4; jj++) {
#pragma unroll
        for (int h = 0; h < 2; h++) {
          __builtin_amdgcn_global_load_lds(apg + (size_t)jj * 8 * lda + h * 64 + k0,
                                           asw + jj * 128 + h * 64, 16, 0, 0);
          __builtin_amdgcn_global_load_lds(bpg + (size_t)jj * 8 * ldb + h * 64 + k0,
                                           bsw + jj * 128 + h * 64, 16, 0, 0);
        }
      }
      __syncthreads();  // drains vmcnt(0): tile resident

#pragma unroll
      for (int s = 0; s < 4; s++) {
        short8 af[4], bfr[4];
#pragma unroll
        for (int i = 0; i < 4; i++) af[i] = As[fra + i * 256 + s * 32];
#pragma unroll
        for (int jj = 0; jj < 4; jj++) bfr[jj] = Bs[frb + jj * 256 + s * 32];
#pragma unroll
        for (int i = 0; i < 4; i++)
#pragma unroll
          for (int jj = 0; jj < 4; jj++)
            acc[i][jj] = __builtin_amdgcn_mfma_f32_16x16x32_bf16(af[i], bfr[jj], acc[i][jj], 0, 0, 0);
      }
      __syncthreads();  // LDS free for next stage
    }

    // epilogue: C/D layout col=lane&15, row=(lane>>4)*4+reg  [m89/m91 verified]
    if (MODE == 1 && bx >= 16) {
      // V block: write transposed into C2[D][MS]
#pragma unroll
      for (int i = 0; i < 4; i++) {
#pragma unroll
        for (int jj = 0; jj < 4; jj++) {
          const int rowb = bm0 + wm * 64 + i * 16 + q4 * 4;
          const int v = (bn0 - 2048) + wn * 64 + jj * 16 + l15;
          bf16 t[4] = {__float2bfloat16(acc[i][jj][0]), __float2bfloat16(acc[i][jj][1]),
                       __float2bfloat16(acc[i][jj][2]), __float2bfloat16(acc[i][jj][3])};
          *(short4v*)(C2 + (size_t)v * MSZ + rowb) = *(short4v*)t;
        }
      }
    } else {
      CT* Cb = Cz;
      int coff = bn0;
      if (MODE == 1) {  // Q|K contiguous: K block sits MS*D after Q
        Cb = Cz + (bx >= 8 ? (size_t)MSZ * DD : 0);
        coff = (bx & 7) * BN;
      }
#pragma unroll
      for (int i = 0; i < 4; i++) {
#pragma unroll
        for (int jj = 0; jj < 4; jj++) {
#pragma unroll
          for (int r = 0; r < 4; r++) {
            const int row = bm0 + wm * 64 + i * 16 + q4 * 4 + r;
            const int col = coff + wn * 64 + jj * 16 + l15;
            cstore(&Cb[(size_t)row * ldc + col], acc[i][jj][r] * scale);
          }
        }
      }
    }
  }
}

// Single-pass register softmax over the causal prefix; one 256-thr block per
// (q,b) row. Zeros above the diagonal so the PV GEMM needs no masking.
__global__ __launch_bounds__(256)
void softmax_rows(const bf16* __restrict__ Sc, bf16* __restrict__ P, int S) {
  const int q = blockIdx.x, b = blockIdx.y;
  const short8* srow = (const short8*)(Sc + ((size_t)b * S + q) * S);
  short8* prow = (short8*)(P + ((size_t)b * S + q) * S);
  const int len = q + 1;
  const int tid = threadIdx.x;
  const int wave = tid >> 6, lane = tid & 63;
  __shared__ float red[10];

  const short8 raw = srow[tid];
  float v[8];
#pragma unroll
  for (int j = 0; j < 8; j++) {
    const int k = tid * 8 + j;
    const float f = __bfloat162float(((const bf16*)&raw)[j]);
    v[j] = (k < len) ? f : -1e30f;
  }

  float m = v[0];
#pragma unroll
  for (int j = 1; j < 8; j++) m = fmaxf(m, v[j]);
#pragma unroll
  for (int o = 32; o; o >>= 1) m = fmaxf(m, __shfl_down(m, o));
  if (lane == 0) red[wave] = m;
  __syncthreads();
  if (tid == 0) red[8] = fmaxf(fmaxf(red[0], red[1]), fmaxf(red[2], red[3]));
  __syncthreads();
  const float M = red[8];

  float e[8], s = 0.f;
#pragma unroll
  for (int j = 0; j < 8; j++) { e[j] = __expf(v[j] - M); s += e[j]; }
#pragma unroll
  for (int o = 32; o; o >>= 1) s += __shfl_down(s, o);
  if (lane == 0) red[4 + wave] = s;
  __syncthreads();
  if (tid == 0) red[9] = red[4] + red[5] + red[6] + red[7];
  __syncthreads();
  const float inv = 1.f / red[9];

  short8 outp;
#pragma unroll
  for (int j = 0; j < 8; j++) {
    const int k = tid * 8 + j;
    ((bf16*)&outp)[j] = __float2bfloat16((k < len) ? e[j] * inv : 0.f);
  }
  prow[tid] = outp;
}

extern "C" void kernel_launch(void* const* d_in, const int* in_sizes, int n_in,
                              void* d_out, int out_size, void* d_ws, size_t ws_size,
                              hipStream_t stream) {
  const float* x  = (const float*)d_in[0];
  const float* Wq = (const float*)d_in[1];
  const float* Wk = (const float*)d_in[2];
  const float* Wv = (const float*)d_in[3];
  float* out = (float*)d_out;

  const int Bb = 4, S = 2048, D = 1024, MS = Bb * S;  // MS = 8192

  // ws layout; P aliases dead xb/W/Q region (consumed before softmax).
  char* ws = (char*)d_ws;
  bf16* xb = (bf16*)ws;                                          // 16.78 MB
  bf16* wb = (bf16*)(ws + (size_t)MS * D * 2);                   // 6.3 MB
  bf16* Q  = (bf16*)(ws + (size_t)MS * D * 2 + 3u * D * D * 2);  // 16.78 MB
  bf16* Kp = Q + (size_t)MS * D;                                 // 16.78 MB (contig after Q)
  bf16* VT = Kp + (size_t)MS * D;                                // 16.78 MB [D,MS]
  bf16* Sc = VT + (size_t)MS * D;                                // 33.55 MB [B,S,S]
  bf16* P  = (bf16*)ws;                                          // aliases xb/W/Q
  (void)Kp;

  dim3 blk(256);

  f2b<<<dim3(MS * D / 4 / 256), blk, 0, stream>>>(x, xb, MS * D);
  f2b3<<<dim3(D * D / 4 / 256, 3), blk, 0, stream>>>(Wq, Wk, Wv, wb, D * D);

  // QKV fused: [Q|K] rows + V transposed (persistent 768 blocks x 2 jobs)
  gemm_bt<1, bf16><<<dim3(768), blk, 0, stream>>>(
      xb, wb, Q, VT, D, D, D, D, 0, 0, 0, 1.f);
  // Sc = (Q K^T)/32, triangular (544 blocks: XCD pair per batch)
  gemm_bt<2, bf16><<<dim3(544), blk, 0, stream>>>(
      Q, Kp, Sc, nullptr, D, D, S, D,
      (long)S * D, (long)S * D, (long)S * S, 0.03125f);
  // P = row-softmax(Sc)
  softmax_rows<<<dim3(S, Bb), blk, 0, stream>>>(Sc, P, S);
  // out = P @ V  (512 blocks: XCD pair per batch, K clipped at diagonal)
  gemm_bt<3, float><<<dim3(512), blk, 0, stream>>>(
      P, VT, out, nullptr, S, MS, D, S,
      (long)S * S, (long)S, (long)S * D, 1.f);
}